// Round 7
// baseline (49.398 us; speedup 1.0000x reference)
//
#include <hip/hip_runtime.h>
#include <math.h>

#define PI_F 3.14159265358979323846f

// QuantumProjection — R17: fine-grained read<->write interleave.
// R16 post-mortem (FAILED 46.1->48.1): deleting the barrier didn't mix streams
// (identical code re-converges; no drift) and cost VGPR 60->80 / occ 30->22%.
// R15 budget: ramp 2 + read 10.5 + VALU 11.4 + write 18.5 ~= 46. Two structural
// serializations: VALU sits BETWEEN read and write phases (memory idle), and the
// one-shot grid ends in a pure write-drain with no reads to overlap.
// R17: each wave runs 4 iterations of {load 4 x-rows (8KB) -> dot -> circuit for
// 4 samples -> out GEMM -> store 4 out-rows (8KB)}. The instruction stream itself
// alternates reads/writes at ~1us grain: stores of pass p drain under loads of
// p+1; VALU always has memory in flight. Enabler: 1-AMP-PER-LANE circuit
// (16 lanes/sample x 4 samples): Rot = 2 shfl + 8 FMA; CNOT = 2 shfl + 2 sel;
// embedding = 3 mul + sign; z = 4-step signed butterfly. Gate coeffs are
// pass-invariant -> precomputed once (u00r==u11r, u01i==u10i: 2 sel/gate, 32 reg).
// Angles: fold result is duplicated mod-16 -> in-group __shfl, no LDS/barrier.
// Kept: R7 (launch_bounds 3/SIMD cap 170 >= ~160 working set), R9 (plain x loads),
// R14 (plain stores == NT), K1 dot+fold verbatim.

typedef float floatx4 __attribute__((ext_vector_type(4)));

static __device__ __forceinline__ float fast_tanh(float a)
{
    a = fminf(fmaxf(a, -15.f), 15.f);
    const float e = __expf(2.f * a);
    return (e - 1.f) / (e + 1.f);
}

// Rot on gate g (precomputed per-lane coeffs), partner = lane ^ M
#define ROT1(g, M) { \
    const float pr = __shfl_xor(ar, (M), 64); \
    const float pi = __shfl_xor(ai, (M), 64); \
    const float nr = gAr[g]*ar - gAi[g]*ai + gBr[g]*pr - gBi[g]*pi; \
    const float ni = gAr[g]*ai + gAi[g]*ar + gBr[g]*pi + gBi[g]*pr; \
    ar = nr; ai = ni; }

// CNOT: control lane-bit position PC (3-ctrl_wire), target xor mask M (1<<(3-tgt))
#define CNOT1(PC, M) { \
    const bool cc = (lane >> (PC)) & 1; \
    const float tr = __shfl_xor(ar, (M), 64); \
    const float ti = __shfl_xor(ai, (M), 64); \
    ar = cc ? tr : ar; ai = cc ? ti : ai; }

// Block = 256 threads = 4 waves; wave owns 16 samples = 4 passes x 4 samples.
__global__ __launch_bounds__(256, 3) void k_fused(
    const float* __restrict__ x,
    const float* __restrict__ preW,
    const float* __restrict__ preb,
    const float* __restrict__ wts,
    const float* __restrict__ postW,
    const float* __restrict__ postb,
    float* __restrict__ out, int B)
{
    const int lane  = threadIdx.x & 63;
    const int wid   = threadIdx.x >> 6;
    const int base  = blockIdx.x * 64;
    const int wbase = base + wid * 16;
    if (base >= B) return;

    // ---- held: preW fragments + bias (K1 dot weights) ----
    float4 wA[4], wB[4];
#pragma unroll
    for (int w = 0; w < 4; ++w) {
        wA[w] = *reinterpret_cast<const float4*>(preW + w * 512 + lane * 4);
        wB[w] = *reinterpret_cast<const float4*>(preW + w * 512 + 256 + lane * 4);
    }
    const float4 pb = *reinterpret_cast<const float4*>(preb);
    const float pb01 = (lane & 1) ? pb.y : pb.x;
    const float pb23 = (lane & 1) ? pb.w : pb.z;
    const float pbv  = (lane & 2) ? pb23 : pb01;

    // ---- held: per-lane Rot coefficients for all 8 gates (pass-invariant) ----
    // qml.Rot: u00=(cp*c,-sp*c) u01=(-cq*s,-sq*s) u10=(cq*s,-sq*s) u11=(cp*c,sp*c)
    // own-coeff cA = ownB?u11:u00 (real part shared), partner cB = ownB?u10:u01
    // (imag part shared) -> 2 selects per gate.
    float gAr[8], gAi[8], gBr[8], gBi[8];
#pragma unroll
    for (int g = 0; g < 8; ++g) {
        const int w = g & 3;                     // g = layer*4 + wire
        const bool ownB = (lane >> (3 - w)) & 1;
        const float ph = wts[g * 3 + 0];
        const float th = wts[g * 3 + 1];
        const float om = wts[g * 3 + 2];
        const float s_ = __sinf(0.5f * th),        c_ = __cosf(0.5f * th);
        const float sp = __sinf(0.5f * (ph + om)), cp = __cosf(0.5f * (ph + om));
        const float sq = __sinf(0.5f * (ph - om)), cq = __cosf(0.5f * (ph - om));
        gAr[g] = cp * c_;
        gAi[g] = ownB ? sp * c_ : -(sp * c_);
        gBr[g] = ownB ? cq * s_ : -(cq * s_);
        gBi[g] = -(sq * s_);
    }

    // ---- held: postW/postb fragments (out GEMM) ----
    const float4* pW4 = reinterpret_cast<const float4*>(postW);
    const float4* pb4 = reinterpret_cast<const float4*>(postb);
    const float4 q0w = pW4[4 * lane + 0], q1w = pW4[4 * lane + 1];
    const float4 q2w = pW4[4 * lane + 2], q3w = pW4[4 * lane + 3];
    const float4 q4w = pW4[4 * (64 + lane) + 0], q5w = pW4[4 * (64 + lane) + 1];
    const float4 q6w = pW4[4 * (64 + lane) + 2], q7w = pW4[4 * (64 + lane) + 3];
    const float4 bb0 = pb4[lane], bb1 = pb4[64 + lane];

    // amp index = lane & 15; bit3=wire0, bit2=wire1, bit1=wire2, bit0=wire3
    const bool sg0 = (lane & 8) != 0;
    const bool sg1 = (lane & 4) != 0;
    const bool sg2 = (lane & 2) != 0;
    const bool sg3 = (lane & 1) != 0;
    const int  pc  = __popc(lane & 15) & 3;      // (-i)^pc embedding phase
    const int  asrc = (lane & 48) + ((lane >> 2) & 12);  // angle shfl base (in-group)

#pragma unroll
    for (int p = 0; p < 4; ++p) {
        const int b0 = wbase + p * 4;

        // ---- load 4 x-rows (8 KB / wave) ----
        float4 xa[4], xb[4];
#pragma unroll
        for (int t = 0; t < 4; ++t) {
            const float* xr = x + (size_t)(b0 + t) * 512;
            xa[t] = *reinterpret_cast<const float4*>(xr + lane * 4);
            xb[t] = *reinterpret_cast<const float4*>(xr + 256 + lane * 4);
        }

        // ---- K1 dot (verbatim) ----
        float acc[4][4];
#pragma unroll
        for (int t = 0; t < 4; ++t) {
#pragma unroll
            for (int w = 0; w < 4; ++w) {
                acc[t][w] = xa[t].x * wA[w].x + xa[t].y * wA[w].y + xa[t].z * wA[w].z + xa[t].w * wA[w].w
                          + xb[t].x * wB[w].x + xb[t].y * wB[w].y + xb[t].z * wB[w].z + xb[t].w * wB[w].w;
            }
        }

        // ---- 17-shfl fold (verbatim); result duplicated mod 16:
        // lane l holds angle(sample b0+((l>>2)&3), wire l&3) ----
        float v[4];
#pragma unroll
        for (int t = 0; t < 4; ++t) {
            float a01 = (lane & 1) ? acc[t][1] : acc[t][0];
            float b01 = (lane & 1) ? acc[t][0] : acc[t][1];
            a01 += __shfl_xor(b01, 1, 64);
            float a23 = (lane & 1) ? acc[t][3] : acc[t][2];
            float b23 = (lane & 1) ? acc[t][2] : acc[t][3];
            a23 += __shfl_xor(b23, 1, 64);
            const float vv = (lane & 2) ? a23 : a01;
            const float uu = (lane & 2) ? a01 : a23;
            v[t] = vv + __shfl_xor(uu, 2, 64);
        }
        float c01 = (lane & 4) ? v[1] : v[0];
        float d01 = (lane & 4) ? v[0] : v[1];
        c01 += __shfl_xor(d01, 4, 64);
        float c23 = (lane & 4) ? v[3] : v[2];
        float d23 = (lane & 4) ? v[2] : v[3];
        c23 += __shfl_xor(d23, 4, 64);
        float m = (lane & 8) ? c23 : c01;
        float n = (lane & 8) ? c01 : c23;
        m += __shfl_xor(n, 8, 64);
        m += __shfl_xor(m, 16, 64);
        m += __shfl_xor(m, 32, 64);
        const float angv = fast_tanh(m + pbv) * PI_F;

        // ---- angle redistribution (in-group): lane l simulates sample t=l>>4 ----
        const float A0 = __shfl(angv, asrc + 0, 64);
        const float A1 = __shfl(angv, asrc + 1, 64);
        const float A2 = __shfl(angv, asrc + 2, 64);
        const float A3 = __shfl(angv, asrc + 3, 64);

        // ---- RX embedding, 1 amp/lane: amp = mag * (-i)^pc ----
        const float s0 = __sinf(0.5f * A0), c0 = __cosf(0.5f * A0);
        const float s1 = __sinf(0.5f * A1), c1 = __cosf(0.5f * A1);
        const float s2 = __sinf(0.5f * A2), c2 = __cosf(0.5f * A2);
        const float s3 = __sinf(0.5f * A3), c3 = __cosf(0.5f * A3);
        const float mag = (sg0 ? s0 : c0) * (sg1 ? s1 : c1)
                        * (sg2 ? s2 : c2) * (sg3 ? s3 : c3);
        float ar = (pc == 0) ? mag : ((pc == 2) ? -mag : 0.f);
        float ai = (pc == 1) ? -mag : ((pc == 3) ? mag : 0.f);

        // ---- layer 0: Rot w0..w3 (masks 8,4,2,1), CNOT ring r=1 ----
        ROT1(0, 8)  ROT1(1, 4)  ROT1(2, 2)  ROT1(3, 1)
        CNOT1(3, 4)  // (0,1)
        CNOT1(2, 2)  // (1,2)
        CNOT1(1, 1)  // (2,3)
        CNOT1(0, 8)  // (3,0)
        // ---- layer 1: Rot w0..w3, CNOT ring r=2 ----
        ROT1(4, 8)  ROT1(5, 4)  ROT1(6, 2)  ROT1(7, 1)
        CNOT1(3, 2)  // (0,2)
        CNOT1(2, 1)  // (1,3)
        CNOT1(1, 8)  // (2,0)
        CNOT1(0, 4)  // (3,1)

        // ---- PauliZ expvals: signed 4-step butterfly within 16-lane group ----
        const float pam = ar * ar + ai * ai;
        float z0 = sg0 ? -pam : pam;
        float z1 = sg1 ? -pam : pam;
        float z2 = sg2 ? -pam : pam;
        float z3 = sg3 ? -pam : pam;
        z0 += __shfl_xor(z0, 1, 64); z0 += __shfl_xor(z0, 2, 64);
        z0 += __shfl_xor(z0, 4, 64); z0 += __shfl_xor(z0, 8, 64);
        z1 += __shfl_xor(z1, 1, 64); z1 += __shfl_xor(z1, 2, 64);
        z1 += __shfl_xor(z1, 4, 64); z1 += __shfl_xor(z1, 8, 64);
        z2 += __shfl_xor(z2, 1, 64); z2 += __shfl_xor(z2, 2, 64);
        z2 += __shfl_xor(z2, 4, 64); z2 += __shfl_xor(z2, 8, 64);
        z3 += __shfl_xor(z3, 1, 64); z3 += __shfl_xor(z3, 2, 64);
        z3 += __shfl_xor(z3, 4, 64); z3 += __shfl_xor(z3, 8, 64);
        // all 16 lanes of group s hold z0..z3 of sample b0+s

        // ---- out GEMM: 4 rows, 2 coalesced float4 stores per lane per row ----
#pragma unroll
        for (int s = 0; s < 4; ++s) {
            const float q0 = __shfl(z0, s * 16, 64);
            const float q1 = __shfl(z1, s * 16, 64);
            const float q2 = __shfl(z2, s * 16, 64);
            const float q3 = __shfl(z3, s * 16, 64);
            floatx4 o0, o1;
            o0.x = fmaf(q3, q0w.w, fmaf(q2, q0w.z, fmaf(q1, q0w.y, fmaf(q0, q0w.x, bb0.x))));
            o0.y = fmaf(q3, q1w.w, fmaf(q2, q1w.z, fmaf(q1, q1w.y, fmaf(q0, q1w.x, bb0.y))));
            o0.z = fmaf(q3, q2w.w, fmaf(q2, q2w.z, fmaf(q1, q2w.y, fmaf(q0, q2w.x, bb0.z))));
            o0.w = fmaf(q3, q3w.w, fmaf(q2, q3w.z, fmaf(q1, q3w.y, fmaf(q0, q3w.x, bb0.w))));
            o1.x = fmaf(q3, q4w.w, fmaf(q2, q4w.z, fmaf(q1, q4w.y, fmaf(q0, q4w.x, bb1.x))));
            o1.y = fmaf(q3, q5w.w, fmaf(q2, q5w.z, fmaf(q1, q5w.y, fmaf(q0, q5w.x, bb1.y))));
            o1.z = fmaf(q3, q6w.w, fmaf(q2, q6w.z, fmaf(q1, q6w.y, fmaf(q0, q6w.x, bb1.z))));
            o1.w = fmaf(q3, q7w.w, fmaf(q2, q7w.z, fmaf(q1, q7w.y, fmaf(q0, q7w.x, bb1.w))));
            float* orow = out + (size_t)(b0 + s) * 512;
            *reinterpret_cast<floatx4*>(orow + 4 * lane) = o0;
            *reinterpret_cast<floatx4*>(orow + 256 + 4 * lane) = o1;
        }
    }
}

extern "C" void kernel_launch(void* const* d_in, const int* in_sizes, int n_in,
                              void* d_out, int out_size, void* d_ws, size_t ws_size,
                              hipStream_t stream)
{
    const float* x     = (const float*)d_in[0];
    const float* preW  = (const float*)d_in[1];
    const float* preb  = (const float*)d_in[2];
    const float* wts   = (const float*)d_in[3];
    const float* postW = (const float*)d_in[4];
    const float* postb = (const float*)d_in[5];
    float* out = (float*)d_out;
    const int B = in_sizes[0] / 512;

    // 4 waves/block, 64 samples/block
    k_fused<<<dim3((B + 63) / 64), dim3(256), 0, stream>>>(
        x, preW, preb, wts, postW, postb, out, B);
}

// Round 8
// 48.594 us; speedup vs baseline: 1.0165x; 1.0165x over previous
//
#include <hip/hip_runtime.h>
#include <math.h>

#define PI_F 3.14159265358979323846f

// QuantumProjection — R18: R13's pipeline skeleton x R15's lean circuit.
// R17 post-mortem (FAILED 49.4): 1-amp/lane circuit didn't cut VALU (shfl-heavy,
// 12.4us abs) and fine interleave bought nothing. Evidence now (R13/R16/R17):
// HBM is ONE ~6.5-7 TB/s pool (m13 copy BW is R+W combined) -> direction mixing
// adds no bandwidth. Only remaining lever: hide the serialized VALU (~11.4us)
// under memory drain. Floor = (66+131)MB/6.7 + ramp ~= 32us.
// R18: wave owns 32 samples = 2 chunks x 16. 8 dot-passes, 2-deep load prefetch
// (R13 skeleton); chunk0 circuit+GEMM runs with chunk1's first 2 passes (16KB)
// in flight; chunk1 dot/circuit runs under chunk0's store drain (stores are
// fire-and-forget). R13's confound (old heavy circuit, 17us VALU) replaced by
// R15's split-state circuit (proven 11.4us, 60 VGPR base). Angle hand-off =
// R16's shuffle redistribution (correctness-proven); occupancy objection void
// because grid = 2048 waves = 2/SIMD is the binding limit anyway.
// Kept: R7 (no reg cap), R9 (plain x loads), R14 (plain stores == NT).

typedef float floatx4 __attribute__((ext_vector_type(4)));

static __device__ __forceinline__ float fast_tanh(float a)
{
    a = fminf(fmaxf(a, -15.f), 15.f);
    const float e = __expf(2.f * a);
    return (e - 1.f) / (e + 1.f);
}

// ---- split-state Rot helpers (R15, unchanged) ----
template<int ST>
__device__ __forceinline__ void rot_inlane(float* ar, float* ai,
    float u00r, float u00i, float u01r, float u01i,
    float u10r, float u10i, float u11r, float u11i)
{
#pragma unroll
    for (int k = 0; k < 4; ++k) {
        if (k & ST) continue;
        const int j = k | ST;
        const float Ar = ar[k], Ai = ai[k], Br = ar[j], Bi = ai[j];
        ar[k] = u00r*Ar - u00i*Ai + u01r*Br - u01i*Bi;
        ai[k] = u00r*Ai + u00i*Ar + u01r*Bi + u01i*Br;
        ar[j] = u10r*Ar - u10i*Ai + u11r*Br - u11i*Bi;
        ai[j] = u10r*Ai + u10i*Ar + u11r*Bi + u11i*Br;
    }
}

template<int XM>
__device__ __forceinline__ void rot_cross(float* ar, float* ai, bool ownB,
    float u00r, float u00i, float u01r, float u01i,
    float u10r, float u10i, float u11r, float u11i)
{
    const float cAr = ownB ? u11r : u00r;
    const float cAi = ownB ? u11i : u00i;
    const float cBr = ownB ? u10r : u01r;
    const float cBi = ownB ? u10i : u01i;
#pragma unroll
    for (int k = 0; k < 4; ++k) {
        const float pr = __shfl_xor(ar[k], XM, 64);
        const float pi = __shfl_xor(ai[k], XM, 64);
        const float vr = ar[k], vi = ai[k];
        ar[k] = cAr*vr - cAi*vi + cBr*pr - cBi*pi;
        ai[k] = cAr*vi + cAi*vr + cBr*pi + cBi*pr;
    }
}

#define ROT_COEFFS(L, W) \
    const float ph = wts[((L)*4+(W))*3+0]; \
    const float th = wts[((L)*4+(W))*3+1]; \
    const float om = wts[((L)*4+(W))*3+2]; \
    const float s_  = __sinf(0.5f*th),        c_  = __cosf(0.5f*th); \
    const float sp_ = __sinf(0.5f*(ph+om)),   cp_ = __cosf(0.5f*(ph+om)); \
    const float sq_ = __sinf(0.5f*(ph-om)),   cq_ = __cosf(0.5f*(ph-om));

#define U_ARGS cp_*c_, -sp_*c_, -cq_*s_, -sq_*s_, cq_*s_, -sq_*s_, cp_*c_, sp_*c_

// Issue one dot-pass's 8 float4 loads (pass p = 4 samples starting at wbase+p*4)
#define ISSUE_PASS(slot, p) { \
    const float* xr_ = x + (size_t)(wbase + (p) * 4) * 512 + lane * 4; \
    bxa[slot][0] = *reinterpret_cast<const float4*>(xr_); \
    bxb[slot][0] = *reinterpret_cast<const float4*>(xr_ + 256); \
    bxa[slot][1] = *reinterpret_cast<const float4*>(xr_ + 512); \
    bxb[slot][1] = *reinterpret_cast<const float4*>(xr_ + 768); \
    bxa[slot][2] = *reinterpret_cast<const float4*>(xr_ + 1024); \
    bxb[slot][2] = *reinterpret_cast<const float4*>(xr_ + 1280); \
    bxa[slot][3] = *reinterpret_cast<const float4*>(xr_ + 1536); \
    bxb[slot][3] = *reinterpret_cast<const float4*>(xr_ + 1792); }

// Consume slot: 4 samples x 4 wires dot + 17-shfl fold -> dest (valid on ALL lanes,
// duplicated mod 16: lane l holds angle(sample pass*4 + ((l>>2)&3), wire l&3))
#define DOTS_FOLD(slot, dest) { \
    float acc[4][4]; \
    _Pragma("unroll") \
    for (int t = 0; t < 4; ++t) { \
        _Pragma("unroll") \
        for (int w = 0; w < 4; ++w) { \
            acc[t][w] = bxa[slot][t].x * wA[w].x + bxa[slot][t].y * wA[w].y \
                      + bxa[slot][t].z * wA[w].z + bxa[slot][t].w * wA[w].w \
                      + bxb[slot][t].x * wB[w].x + bxb[slot][t].y * wB[w].y \
                      + bxb[slot][t].z * wB[w].z + bxb[slot][t].w * wB[w].w; \
        } \
    } \
    float v[4]; \
    _Pragma("unroll") \
    for (int t = 0; t < 4; ++t) { \
        float a01 = (lane & 1) ? acc[t][1] : acc[t][0]; \
        float b01 = (lane & 1) ? acc[t][0] : acc[t][1]; \
        a01 += __shfl_xor(b01, 1, 64); \
        float a23 = (lane & 1) ? acc[t][3] : acc[t][2]; \
        float b23 = (lane & 1) ? acc[t][2] : acc[t][3]; \
        a23 += __shfl_xor(b23, 1, 64); \
        const float vv = (lane & 2) ? a23 : a01; \
        const float uu = (lane & 2) ? a01 : a23; \
        v[t] = vv + __shfl_xor(uu, 2, 64); \
    } \
    float c01 = (lane & 4) ? v[1] : v[0]; \
    float d01 = (lane & 4) ? v[0] : v[1]; \
    c01 += __shfl_xor(d01, 4, 64); \
    float c23 = (lane & 4) ? v[3] : v[2]; \
    float d23 = (lane & 4) ? v[2] : v[3]; \
    c23 += __shfl_xor(d23, 4, 64); \
    float m_ = (lane & 8) ? c23 : c01; \
    float n_ = (lane & 8) ? c01 : c23; \
    m_ += __shfl_xor(n_, 8, 64); \
    m_ += __shfl_xor(m_, 16, 64); \
    m_ += __shfl_xor(m_, 32, 64); \
    dest = fast_tanh(m_ + pbv) * PI_F; }

// Block = 256 threads = 4 waves; each wave owns 32 consecutive samples (2 chunks x 16).
__global__ __launch_bounds__(256) void k_fused(
    const float* __restrict__ x,
    const float* __restrict__ preW,
    const float* __restrict__ preb,
    const float* __restrict__ wts,
    const float* __restrict__ postW,
    const float* __restrict__ postb,
    float* __restrict__ out, int B)
{
    const int lane  = threadIdx.x & 63;
    const int wid   = threadIdx.x >> 6;
    const int wbase = blockIdx.x * 128 + wid * 32;
    if (wbase >= B) return;

    // ---- held: preW fragments + bias ----
    float4 wA[4], wB[4];
#pragma unroll
    for (int w = 0; w < 4; ++w) {
        wA[w] = *reinterpret_cast<const float4*>(preW + w * 512 + lane * 4);
        wB[w] = *reinterpret_cast<const float4*>(preW + w * 512 + 256 + lane * 4);
    }
    const float4 pb = *reinterpret_cast<const float4*>(preb);
    const float pb01 = (lane & 1) ? pb.y : pb.x;
    const float pb23 = (lane & 1) ? pb.w : pb.z;
    const float pbv  = (lane & 2) ? pb23 : pb01;

    // ---- held: postW/postb fragments ----
    const float4* pW4 = reinterpret_cast<const float4*>(postW);
    const float4* pb4 = reinterpret_cast<const float4*>(postb);
    const float4 q0w = pW4[4 * lane + 0], q1w = pW4[4 * lane + 1];
    const float4 q2w = pW4[4 * lane + 2], q3w = pW4[4 * lane + 3];
    const float4 q4w = pW4[4 * (64 + lane) + 0], q5w = pW4[4 * (64 + lane) + 1];
    const float4 q6w = pW4[4 * (64 + lane) + 2], q7w = pW4[4 * (64 + lane) + 3];
    const float4 bb0 = pb4[lane], bb1 = pb4[64 + lane];

    const bool lb3 = (lane & 2) != 0;            // amp bit3 (wire0)
    const bool lb2 = (lane & 1) != 0;            // amp bit2 (wire1)
    const int  sb  = (lane & 48) + 4 * ((lane >> 2) & 3);  // angle shfl base

    float4 bxa[2][4], bxb[2][4];                 // 2-deep pass prefetch buffers

    // circuit + out GEMM for one 16-sample chunk (R15/R16 verbatim)
    auto chunk_body = [&](int cb, float a0, float a1, float a2, float a3) {
        // shuffle redistribution: lane l simulates sample sid=l>>2 of this chunk
        const float comb = (lane & 32) ? ((lane & 16) ? a3 : a2)
                                       : ((lane & 16) ? a1 : a0);
        const float A0 = __shfl(comb, sb + 0, 64);
        const float A1 = __shfl(comb, sb + 1, 64);
        const float A2 = __shfl(comb, sb + 2, 64);
        const float A3 = __shfl(comb, sb + 3, 64);

        const float s0 = __sinf(0.5f * A0), c0 = __cosf(0.5f * A0);
        const float s1 = __sinf(0.5f * A1), c1 = __cosf(0.5f * A1);
        const float s2 = __sinf(0.5f * A2), c2 = __cosf(0.5f * A2);
        const float s3 = __sinf(0.5f * A3), c3 = __cosf(0.5f * A3);

        const float mhi = (lb3 ? s0 : c0) * (lb2 ? s1 : c1);
        const float hr  = lb3 ? (lb2 ? -mhi : 0.f) : (lb2 ? 0.f : mhi);
        const float hi  = (lb3 != lb2) ? -mhi : 0.f;
        const float low0 = c2 * c3, low1 = c2 * s3, low2 = s2 * c3, low3 = s2 * s3;

        float ar[4], ai[4];
        ar[0] =  hr * low0;  ai[0] =  hi * low0;
        ar[1] =  hi * low1;  ai[1] = -hr * low1;
        ar[2] =  hi * low2;  ai[2] = -hr * low2;
        ar[3] = -hr * low3;  ai[3] = -hi * low3;

        // layer 0
        { ROT_COEFFS(0, 0); rot_cross<2>(ar, ai, lb3, U_ARGS); }
        { ROT_COEFFS(0, 1); rot_cross<1>(ar, ai, lb2, U_ARGS); }
        { ROT_COEFFS(0, 2); rot_inlane<2>(ar, ai, U_ARGS); }
        { ROT_COEFFS(0, 3); rot_inlane<1>(ar, ai, U_ARGS); }
        {   // cnot<0,1>
#pragma unroll
            for (int k = 0; k < 4; ++k) {
                const float tr = __shfl_xor(ar[k], 1, 64);
                const float ti = __shfl_xor(ai[k], 1, 64);
                ar[k] = lb3 ? tr : ar[k];
                ai[k] = lb3 ? ti : ai[k];
            }
        }
        {   // cnot<1,2>
            const float t0r = ar[0], t0i = ai[0], t1r = ar[1], t1i = ai[1];
            ar[0] = lb2 ? ar[2] : ar[0];  ai[0] = lb2 ? ai[2] : ai[0];
            ar[1] = lb2 ? ar[3] : ar[1];  ai[1] = lb2 ? ai[3] : ai[1];
            ar[2] = lb2 ? t0r   : ar[2];  ai[2] = lb2 ? t0i   : ai[2];
            ar[3] = lb2 ? t1r   : ar[3];  ai[3] = lb2 ? t1i   : ai[3];
        }
        {   // cnot<2,3>: in-lane swap k2<->k3
            float t;
            t = ar[2]; ar[2] = ar[3]; ar[3] = t;
            t = ai[2]; ai[2] = ai[3]; ai[3] = t;
        }
        {   // cnot<3,0>: k in {1,3} exchange across lane^2
            ar[1] = __shfl_xor(ar[1], 2, 64);  ai[1] = __shfl_xor(ai[1], 2, 64);
            ar[3] = __shfl_xor(ar[3], 2, 64);  ai[3] = __shfl_xor(ai[3], 2, 64);
        }

        // layer 1
        { ROT_COEFFS(1, 0); rot_cross<2>(ar, ai, lb3, U_ARGS); }
        { ROT_COEFFS(1, 1); rot_cross<1>(ar, ai, lb2, U_ARGS); }
        { ROT_COEFFS(1, 2); rot_inlane<2>(ar, ai, U_ARGS); }
        { ROT_COEFFS(1, 3); rot_inlane<1>(ar, ai, U_ARGS); }
        {   // cnot<0,2>
            const float t0r = ar[0], t0i = ai[0], t1r = ar[1], t1i = ai[1];
            ar[0] = lb3 ? ar[2] : ar[0];  ai[0] = lb3 ? ai[2] : ai[0];
            ar[1] = lb3 ? ar[3] : ar[1];  ai[1] = lb3 ? ai[3] : ai[1];
            ar[2] = lb3 ? t0r   : ar[2];  ai[2] = lb3 ? t0i   : ai[2];
            ar[3] = lb3 ? t1r   : ar[3];  ai[3] = lb3 ? t1i   : ai[3];
        }
        {   // cnot<1,3>
            const float t0r = ar[0], t0i = ai[0], t2r = ar[2], t2i = ai[2];
            ar[0] = lb2 ? ar[1] : ar[0];  ai[0] = lb2 ? ai[1] : ai[0];
            ar[1] = lb2 ? t0r   : ar[1];  ai[1] = lb2 ? t0i   : ai[1];
            ar[2] = lb2 ? ar[3] : ar[2];  ai[2] = lb2 ? ai[3] : ai[2];
            ar[3] = lb2 ? t2r   : ar[3];  ai[3] = lb2 ? t2i   : ai[3];
        }
        {   // cnot<2,0>
            ar[2] = __shfl_xor(ar[2], 2, 64);  ai[2] = __shfl_xor(ai[2], 2, 64);
            ar[3] = __shfl_xor(ar[3], 2, 64);  ai[3] = __shfl_xor(ai[3], 2, 64);
        }
        {   // cnot<3,1>
            ar[1] = __shfl_xor(ar[1], 1, 64);  ai[1] = __shfl_xor(ai[1], 1, 64);
            ar[3] = __shfl_xor(ar[3], 1, 64);  ai[3] = __shfl_xor(ai[3], 1, 64);
        }

        // PauliZ expvals
        const float p0 = ar[0]*ar[0] + ai[0]*ai[0];
        const float p1 = ar[1]*ar[1] + ai[1]*ai[1];
        const float p2 = ar[2]*ar[2] + ai[2]*ai[2];
        const float p3 = ar[3]*ar[3] + ai[3]*ai[3];
        const float s01 = p0 + p1, s23 = p2 + p3;
        const float sum = s01 + s23;
        float z0 = lb3 ? -sum : sum;
        float z1 = lb2 ? -sum : sum;
        float z2 = s01 - s23;
        float z3 = (p0 - p1) + (p2 - p3);
        z0 += __shfl_xor(z0, 1, 64);  z0 += __shfl_xor(z0, 2, 64);
        z1 += __shfl_xor(z1, 1, 64);  z1 += __shfl_xor(z1, 2, 64);
        z2 += __shfl_xor(z2, 1, 64);  z2 += __shfl_xor(z2, 2, 64);
        z3 += __shfl_xor(z3, 1, 64);  z3 += __shfl_xor(z3, 2, 64);

        // out GEMM: 16 rows, 2 coalesced float4 stores per lane per row
#pragma unroll
        for (int s = 0; s < 16; ++s) {
            const float q0 = __shfl(z0, s * 4, 64);
            const float q1 = __shfl(z1, s * 4, 64);
            const float q2 = __shfl(z2, s * 4, 64);
            const float q3 = __shfl(z3, s * 4, 64);
            floatx4 o0, o1;
            o0.x = fmaf(q3, q0w.w, fmaf(q2, q0w.z, fmaf(q1, q0w.y, fmaf(q0, q0w.x, bb0.x))));
            o0.y = fmaf(q3, q1w.w, fmaf(q2, q1w.z, fmaf(q1, q1w.y, fmaf(q0, q1w.x, bb0.y))));
            o0.z = fmaf(q3, q2w.w, fmaf(q2, q2w.z, fmaf(q1, q2w.y, fmaf(q0, q2w.x, bb0.z))));
            o0.w = fmaf(q3, q3w.w, fmaf(q2, q3w.z, fmaf(q1, q3w.y, fmaf(q0, q3w.x, bb0.w))));
            o1.x = fmaf(q3, q4w.w, fmaf(q2, q4w.z, fmaf(q1, q4w.y, fmaf(q0, q4w.x, bb1.x))));
            o1.y = fmaf(q3, q5w.w, fmaf(q2, q5w.z, fmaf(q1, q5w.y, fmaf(q0, q5w.x, bb1.y))));
            o1.z = fmaf(q3, q6w.w, fmaf(q2, q6w.z, fmaf(q1, q6w.y, fmaf(q0, q6w.x, bb1.z))));
            o1.w = fmaf(q3, q7w.w, fmaf(q2, q7w.z, fmaf(q1, q7w.y, fmaf(q0, q7w.x, bb1.w))));
            float* orow = out + (size_t)(cb + s) * 512;
            *reinterpret_cast<floatx4*>(orow + 4 * lane) = o0;
            *reinterpret_cast<floatx4*>(orow + 256 + 4 * lane) = o1;
        }
    };

    float a0, a1, a2, a3;

    // -------- 8 passes (2 chunks), loads 2 passes ahead (R13 skeleton) --------
    ISSUE_PASS(0, 0);
    ISSUE_PASS(1, 1);
    DOTS_FOLD(0, a0);  ISSUE_PASS(0, 2);
    DOTS_FOLD(1, a1);  ISSUE_PASS(1, 3);
    DOTS_FOLD(0, a2);  ISSUE_PASS(0, 4);      // pass 4 = chunk1's first
    DOTS_FOLD(1, a3);  ISSUE_PASS(1, 5);
    chunk_body(wbase, a0, a1, a2, a3);        // chunk0; passes 4,5 (16KB) in flight
    DOTS_FOLD(0, a0);  ISSUE_PASS(0, 6);
    DOTS_FOLD(1, a1);  ISSUE_PASS(1, 7);
    DOTS_FOLD(0, a2);
    DOTS_FOLD(1, a3);
    chunk_body(wbase + 16, a0, a1, a2, a3);   // chunk1; chunk0 stores draining
}

extern "C" void kernel_launch(void* const* d_in, const int* in_sizes, int n_in,
                              void* d_out, int out_size, void* d_ws, size_t ws_size,
                              hipStream_t stream)
{
    const float* x     = (const float*)d_in[0];
    const float* preW  = (const float*)d_in[1];
    const float* preb  = (const float*)d_in[2];
    const float* wts   = (const float*)d_in[3];
    const float* postW = (const float*)d_in[4];
    const float* postb = (const float*)d_in[5];
    float* out = (float*)d_out;
    const int B = in_sizes[0] / 512;

    // 4 waves/block x 32 samples/wave = 128 samples/block -> 512 blocks
    k_fused<<<dim3((B + 127) / 128), dim3(256), 0, stream>>>(
        x, preW, preb, wts, postW, postb, out, B);
}

// Round 9
// 46.926 us; speedup vs baseline: 1.0527x; 1.0356x over previous
//
#include <hip/hip_runtime.h>
#include <math.h>

#define PI_F 3.14159265358979323846f

// QuantumProjection — R19: producer/consumer WAVE SPECIALIZATION.
// R18 post-mortem: in-wave prefetch was silently destroyed by the compiler
// (VGPR=88 << the ~160 needed to hold the prefetch -> loads sunk to their use),
// and gfx9 vmcnt is one in-order FIFO for loads AND stores -> waiting a prefetched
// load drains the stores issued after it. Third failed symmetric-wave overlap.
// R19 removes both killers: producer waves (0-3) ONLY load (x -> dot -> fold ->
// angles to LDS + flag), consumer waves (4-7) ONLY store (circuit -> out GEMM).
// No vmcnt coupling (different waves), no sinking (LDS hand-off + fence pins the
// schedule), no lockstep (groups are at different phases by construction, so HBM
// sees reads and writes concurrently through the whole middle of the kernel).
// Sync: per-16-sample chunk flag in LDS; producer: ds_writes -> __threadfence_block
// -> flag=1; consumer: spin volatile read + s_sleep -> fence -> ds_read angles.
// Producers never wait on consumers (angle buffer fully sized) -> no deadlock.
// Components verbatim: K1 dot+fold (R12), split-state circuit + GEMM (R15).
// Kept: R7 (no reg cap), R9 (plain x loads), R14 (plain stores).
// Pool model: 770 KB/CU ~= 29.5us; VALU ~5.8us/SIMD hidden; predict 36-42us.

typedef float floatx4 __attribute__((ext_vector_type(4)));

static __device__ __forceinline__ float fast_tanh(float a)
{
    a = fminf(fmaxf(a, -15.f), 15.f);
    const float e = __expf(2.f * a);
    return (e - 1.f) / (e + 1.f);
}

// ---- split-state Rot helpers (R15, unchanged) ----
template<int ST>
__device__ __forceinline__ void rot_inlane(float* ar, float* ai,
    float u00r, float u00i, float u01r, float u01i,
    float u10r, float u10i, float u11r, float u11i)
{
#pragma unroll
    for (int k = 0; k < 4; ++k) {
        if (k & ST) continue;
        const int j = k | ST;
        const float Ar = ar[k], Ai = ai[k], Br = ar[j], Bi = ai[j];
        ar[k] = u00r*Ar - u00i*Ai + u01r*Br - u01i*Bi;
        ai[k] = u00r*Ai + u00i*Ar + u01r*Bi + u01i*Br;
        ar[j] = u10r*Ar - u10i*Ai + u11r*Br - u11i*Bi;
        ai[j] = u10r*Ai + u10i*Ar + u11r*Bi + u11i*Br;
    }
}

template<int XM>
__device__ __forceinline__ void rot_cross(float* ar, float* ai, bool ownB,
    float u00r, float u00i, float u01r, float u01i,
    float u10r, float u10i, float u11r, float u11i)
{
    const float cAr = ownB ? u11r : u00r;
    const float cAi = ownB ? u11i : u00i;
    const float cBr = ownB ? u10r : u01r;
    const float cBi = ownB ? u10i : u01i;
#pragma unroll
    for (int k = 0; k < 4; ++k) {
        const float pr = __shfl_xor(ar[k], XM, 64);
        const float pi = __shfl_xor(ai[k], XM, 64);
        const float vr = ar[k], vi = ai[k];
        ar[k] = cAr*vr - cAi*vi + cBr*pr - cBi*pi;
        ai[k] = cAr*vi + cAi*vr + cBr*pi + cBi*pr;
    }
}

#define ROT_COEFFS(L, W) \
    const float ph = wts[((L)*4+(W))*3+0]; \
    const float th = wts[((L)*4+(W))*3+1]; \
    const float om = wts[((L)*4+(W))*3+2]; \
    const float s_  = __sinf(0.5f*th),        c_  = __cosf(0.5f*th); \
    const float sp_ = __sinf(0.5f*(ph+om)),   cp_ = __cosf(0.5f*(ph+om)); \
    const float sq_ = __sinf(0.5f*(ph-om)),   cq_ = __cosf(0.5f*(ph-om));

#define U_ARGS cp_*c_, -sp_*c_, -cq_*s_, -sq_*s_, cq_*s_, -sq_*s_, cp_*c_, sp_*c_

// Block = 512 threads = 8 waves = 128 samples.
// Waves 0-3: producers (32 samples each, 8 dot-passes). Waves 4-7: consumers
// (32 samples each = 2 chunks of 16, circuit + out GEMM).
__global__ __launch_bounds__(512) void k_fused(
    const float* __restrict__ x,
    const float* __restrict__ preW,
    const float* __restrict__ preb,
    const float* __restrict__ wts,
    const float* __restrict__ postW,
    const float* __restrict__ postb,
    float* __restrict__ out, int B)
{
    const int lane = threadIdx.x & 63;
    const int wid  = threadIdx.x >> 6;           // 0..7
    const int base = blockIdx.x * 128;
    if (base >= B) return;

    __shared__ float4 angLds[128];               // [sampleLocal] -> 4 angles
    __shared__ volatile int flag[8];             // per-16-sample chunk ready flags
    if (threadIdx.x < 8) flag[threadIdx.x] = 0;
    __syncthreads();                             // only barrier; everyone at start

    if (wid < 4) {
        // ================= PRODUCER: K1 dot + fold -> LDS =================
        const int p = wid;                       // producer id 0..3, samples [32p,+32)
        float4 wA[4], wB[4];
#pragma unroll
        for (int w = 0; w < 4; ++w) {
            wA[w] = *reinterpret_cast<const float4*>(preW + w * 512 + lane * 4);
            wB[w] = *reinterpret_cast<const float4*>(preW + w * 512 + 256 + lane * 4);
        }
        const float4 pb = *reinterpret_cast<const float4*>(preb);
        const float pb01 = (lane & 1) ? pb.y : pb.x;
        const float pb23 = (lane & 1) ? pb.w : pb.z;
        const float pbv  = (lane & 2) ? pb23 : pb01;

#pragma unroll 1
        for (int j = 0; j < 8; ++j) {            // pass j: 4 samples
            const int b0 = base + 32 * p + 4 * j;

            float4 xa[4], xb[4];
#pragma unroll
            for (int t = 0; t < 4; ++t) {
                const float* xr = x + (size_t)(b0 + t) * 512;
                xa[t] = *reinterpret_cast<const float4*>(xr + lane * 4);
                xb[t] = *reinterpret_cast<const float4*>(xr + 256 + lane * 4);
            }

            float acc[4][4];
#pragma unroll
            for (int t = 0; t < 4; ++t) {
#pragma unroll
                for (int w = 0; w < 4; ++w) {
                    acc[t][w] = xa[t].x * wA[w].x + xa[t].y * wA[w].y + xa[t].z * wA[w].z + xa[t].w * wA[w].w
                              + xb[t].x * wB[w].x + xb[t].y * wB[w].y + xb[t].z * wB[w].z + xb[t].w * wB[w].w;
                }
            }

            // 17-shfl fold (verbatim): lane l (<16) holds angle(sample b0+(l>>2), wire l&3)
            float v[4];
#pragma unroll
            for (int t = 0; t < 4; ++t) {
                float a01 = (lane & 1) ? acc[t][1] : acc[t][0];
                float b01 = (lane & 1) ? acc[t][0] : acc[t][1];
                a01 += __shfl_xor(b01, 1, 64);
                float a23 = (lane & 1) ? acc[t][3] : acc[t][2];
                float b23 = (lane & 1) ? acc[t][2] : acc[t][3];
                a23 += __shfl_xor(b23, 1, 64);
                const float vv = (lane & 2) ? a23 : a01;
                const float uu = (lane & 2) ? a01 : a23;
                v[t] = vv + __shfl_xor(uu, 2, 64);
            }
            float c01 = (lane & 4) ? v[1] : v[0];
            float d01 = (lane & 4) ? v[0] : v[1];
            c01 += __shfl_xor(d01, 4, 64);
            float c23 = (lane & 4) ? v[3] : v[2];
            float d23 = (lane & 4) ? v[2] : v[3];
            c23 += __shfl_xor(d23, 4, 64);
            float m = (lane & 8) ? c23 : c01;
            float n = (lane & 8) ? c01 : c23;
            m += __shfl_xor(n, 8, 64);
            m += __shfl_xor(m, 16, 64);
            m += __shfl_xor(m, 32, 64);
            const float angv = fast_tanh(m + pbv) * PI_F;

            // chunk c = 2p + (j>>2); sample-in-chunk = 4*(j&3) + (lane>>2)
            if (lane < 16) {
                float* arow = reinterpret_cast<float*>(
                    &angLds[16 * (2 * p + (j >> 2)) + 4 * (j & 3) + (lane >> 2)]);
                arow[lane & 3] = angv;
            }
            if ((j & 3) == 3) {                  // chunk complete -> publish
                __threadfence_block();           // drain ds_writes before flag
                if (lane == 0) flag[2 * p + (j >> 2)] = 1;
            }
        }
    } else {
        // ================= CONSUMER: circuit + out GEMM =================
        const int q = wid - 4;                   // consumer id 0..3, chunks 2q, 2q+1
        const float4* pW4 = reinterpret_cast<const float4*>(postW);
        const float4* pb4 = reinterpret_cast<const float4*>(postb);
        const float4 q0w = pW4[4 * lane + 0], q1w = pW4[4 * lane + 1];
        const float4 q2w = pW4[4 * lane + 2], q3w = pW4[4 * lane + 3];
        const float4 q4w = pW4[4 * (64 + lane) + 0], q5w = pW4[4 * (64 + lane) + 1];
        const float4 q6w = pW4[4 * (64 + lane) + 2], q7w = pW4[4 * (64 + lane) + 3];
        const float4 bb0 = pb4[lane], bb1 = pb4[64 + lane];

        const bool lb3 = (lane & 2) != 0;        // amp bit3 (wire0)
        const bool lb2 = (lane & 1) != 0;        // amp bit2 (wire1)
        const int  sid = lane >> 2;              // sample in chunk, 0..15

#pragma unroll 1
        for (int h = 0; h < 2; ++h) {
            const int c = 2 * q + h;
            while (flag[c] == 0) __builtin_amdgcn_s_sleep(1);
            __threadfence_block();               // acquire: see producer ds_writes

            const float4 ang = angLds[16 * c + sid];

            const float s0 = __sinf(0.5f * ang.x), c0 = __cosf(0.5f * ang.x);
            const float s1 = __sinf(0.5f * ang.y), c1 = __cosf(0.5f * ang.y);
            const float s2 = __sinf(0.5f * ang.z), c2 = __cosf(0.5f * ang.z);
            const float s3 = __sinf(0.5f * ang.w), c3 = __cosf(0.5f * ang.w);

            const float mhi = (lb3 ? s0 : c0) * (lb2 ? s1 : c1);
            const float hr  = lb3 ? (lb2 ? -mhi : 0.f) : (lb2 ? 0.f : mhi);
            const float hi  = (lb3 != lb2) ? -mhi : 0.f;
            const float low0 = c2 * c3, low1 = c2 * s3, low2 = s2 * c3, low3 = s2 * s3;

            float ar[4], ai[4];
            ar[0] =  hr * low0;  ai[0] =  hi * low0;
            ar[1] =  hi * low1;  ai[1] = -hr * low1;
            ar[2] =  hi * low2;  ai[2] = -hr * low2;
            ar[3] = -hr * low3;  ai[3] = -hi * low3;

            // layer 0
            { ROT_COEFFS(0, 0); rot_cross<2>(ar, ai, lb3, U_ARGS); }
            { ROT_COEFFS(0, 1); rot_cross<1>(ar, ai, lb2, U_ARGS); }
            { ROT_COEFFS(0, 2); rot_inlane<2>(ar, ai, U_ARGS); }
            { ROT_COEFFS(0, 3); rot_inlane<1>(ar, ai, U_ARGS); }
            {   // cnot<0,1>
#pragma unroll
                for (int k = 0; k < 4; ++k) {
                    const float tr = __shfl_xor(ar[k], 1, 64);
                    const float ti = __shfl_xor(ai[k], 1, 64);
                    ar[k] = lb3 ? tr : ar[k];
                    ai[k] = lb3 ? ti : ai[k];
                }
            }
            {   // cnot<1,2>
                const float t0r = ar[0], t0i = ai[0], t1r = ar[1], t1i = ai[1];
                ar[0] = lb2 ? ar[2] : ar[0];  ai[0] = lb2 ? ai[2] : ai[0];
                ar[1] = lb2 ? ar[3] : ar[1];  ai[1] = lb2 ? ai[3] : ai[1];
                ar[2] = lb2 ? t0r   : ar[2];  ai[2] = lb2 ? t0i   : ai[2];
                ar[3] = lb2 ? t1r   : ar[3];  ai[3] = lb2 ? t1i   : ai[3];
            }
            {   // cnot<2,3>: in-lane swap k2<->k3
                float t;
                t = ar[2]; ar[2] = ar[3]; ar[3] = t;
                t = ai[2]; ai[2] = ai[3]; ai[3] = t;
            }
            {   // cnot<3,0>: k in {1,3} exchange across lane^2
                ar[1] = __shfl_xor(ar[1], 2, 64);  ai[1] = __shfl_xor(ai[1], 2, 64);
                ar[3] = __shfl_xor(ar[3], 2, 64);  ai[3] = __shfl_xor(ai[3], 2, 64);
            }

            // layer 1
            { ROT_COEFFS(1, 0); rot_cross<2>(ar, ai, lb3, U_ARGS); }
            { ROT_COEFFS(1, 1); rot_cross<1>(ar, ai, lb2, U_ARGS); }
            { ROT_COEFFS(1, 2); rot_inlane<2>(ar, ai, U_ARGS); }
            { ROT_COEFFS(1, 3); rot_inlane<1>(ar, ai, U_ARGS); }
            {   // cnot<0,2>
                const float t0r = ar[0], t0i = ai[0], t1r = ar[1], t1i = ai[1];
                ar[0] = lb3 ? ar[2] : ar[0];  ai[0] = lb3 ? ai[2] : ai[0];
                ar[1] = lb3 ? ar[3] : ar[1];  ai[1] = lb3 ? ai[3] : ai[1];
                ar[2] = lb3 ? t0r   : ar[2];  ai[2] = lb3 ? t0i   : ai[2];
                ar[3] = lb3 ? t1r   : ar[3];  ai[3] = lb3 ? t1i   : ai[3];
            }
            {   // cnot<1,3>
                const float t0r = ar[0], t0i = ai[0], t2r = ar[2], t2i = ai[2];
                ar[0] = lb2 ? ar[1] : ar[0];  ai[0] = lb2 ? ai[1] : ai[0];
                ar[1] = lb2 ? t0r   : ar[1];  ai[1] = lb2 ? t0i   : ai[1];
                ar[2] = lb2 ? ar[3] : ar[2];  ai[2] = lb2 ? ai[3] : ai[2];
                ar[3] = lb2 ? t2r   : ar[3];  ai[3] = lb2 ? t2i   : ai[3];
            }
            {   // cnot<2,0>
                ar[2] = __shfl_xor(ar[2], 2, 64);  ai[2] = __shfl_xor(ai[2], 2, 64);
                ar[3] = __shfl_xor(ar[3], 2, 64);  ai[3] = __shfl_xor(ai[3], 2, 64);
            }
            {   // cnot<3,1>
                ar[1] = __shfl_xor(ar[1], 1, 64);  ai[1] = __shfl_xor(ai[1], 1, 64);
                ar[3] = __shfl_xor(ar[3], 1, 64);  ai[3] = __shfl_xor(ai[3], 1, 64);
            }

            // PauliZ expvals
            const float p0 = ar[0]*ar[0] + ai[0]*ai[0];
            const float p1 = ar[1]*ar[1] + ai[1]*ai[1];
            const float p2 = ar[2]*ar[2] + ai[2]*ai[2];
            const float p3 = ar[3]*ar[3] + ai[3]*ai[3];
            const float s01 = p0 + p1, s23 = p2 + p3;
            const float sum = s01 + s23;
            float z0 = lb3 ? -sum : sum;
            float z1 = lb2 ? -sum : sum;
            float z2 = s01 - s23;
            float z3 = (p0 - p1) + (p2 - p3);
            z0 += __shfl_xor(z0, 1, 64);  z0 += __shfl_xor(z0, 2, 64);
            z1 += __shfl_xor(z1, 1, 64);  z1 += __shfl_xor(z1, 2, 64);
            z2 += __shfl_xor(z2, 1, 64);  z2 += __shfl_xor(z2, 2, 64);
            z3 += __shfl_xor(z3, 1, 64);  z3 += __shfl_xor(z3, 2, 64);

            // out GEMM: 16 rows, 2 coalesced float4 stores per lane per row
#pragma unroll
            for (int s = 0; s < 16; ++s) {
                const float q0 = __shfl(z0, s * 4, 64);
                const float q1 = __shfl(z1, s * 4, 64);
                const float q2 = __shfl(z2, s * 4, 64);
                const float q3 = __shfl(z3, s * 4, 64);
                floatx4 o0, o1;
                o0.x = fmaf(q3, q0w.w, fmaf(q2, q0w.z, fmaf(q1, q0w.y, fmaf(q0, q0w.x, bb0.x))));
                o0.y = fmaf(q3, q1w.w, fmaf(q2, q1w.z, fmaf(q1, q1w.y, fmaf(q0, q1w.x, bb0.y))));
                o0.z = fmaf(q3, q2w.w, fmaf(q2, q2w.z, fmaf(q1, q2w.y, fmaf(q0, q2w.x, bb0.z))));
                o0.w = fmaf(q3, q3w.w, fmaf(q2, q3w.z, fmaf(q1, q3w.y, fmaf(q0, q3w.x, bb0.w))));
                o1.x = fmaf(q3, q4w.w, fmaf(q2, q4w.z, fmaf(q1, q4w.y, fmaf(q0, q4w.x, bb1.x))));
                o1.y = fmaf(q3, q5w.w, fmaf(q2, q5w.z, fmaf(q1, q5w.y, fmaf(q0, q5w.x, bb1.y))));
                o1.z = fmaf(q3, q6w.w, fmaf(q2, q6w.z, fmaf(q1, q6w.y, fmaf(q0, q6w.x, bb1.z))));
                o1.w = fmaf(q3, q7w.w, fmaf(q2, q7w.z, fmaf(q1, q7w.y, fmaf(q0, q7w.x, bb1.w))));
                float* orow = out + (size_t)(base + 16 * c + s) * 512;
                *reinterpret_cast<floatx4*>(orow + 4 * lane) = o0;
                *reinterpret_cast<floatx4*>(orow + 256 + 4 * lane) = o1;
            }
        }
    }
}

extern "C" void kernel_launch(void* const* d_in, const int* in_sizes, int n_in,
                              void* d_out, int out_size, void* d_ws, size_t ws_size,
                              hipStream_t stream)
{
    const float* x     = (const float*)d_in[0];
    const float* preW  = (const float*)d_in[1];
    const float* preb  = (const float*)d_in[2];
    const float* wts   = (const float*)d_in[3];
    const float* postW = (const float*)d_in[4];
    const float* postb = (const float*)d_in[5];
    float* out = (float*)d_out;
    const int B = in_sizes[0] / 512;

    // 8 waves/block (4 producers + 4 consumers), 128 samples/block -> 512 blocks
    k_fused<<<dim3((B + 127) / 128), dim3(512), 0, stream>>>(
        x, preW, preb, wts, postW, postb, out, B);
}

// Round 10
// 45.634 us; speedup vs baseline: 1.0825x; 1.0283x over previous
//
#include <hip/hip_runtime.h>
#include <math.h>

#define PI_F 3.14159265358979323846f

// QuantumProjection — R20: R15 base (best, 46.1us), ONE change: packed-FP32
// (v_pk_fma_f32 dual-issue) for the two big FMA blocks (dot 512, GEMM 512 /wave).
// R19 post-mortem: wave specialization null (46.9) — 4th overlap structure to
// land on ~46. Accepted: read + VALU + write sum serially here regardless of
// instruction arrangement. Floor ~32us (66+131 MB @ ~6.7TB/s + ramp); excess =
// VALU. Lever: halve the packable FMA count.
//  - dot: preW held TRANSPOSED as float2 pairs over wires ({w0,w1},{w2,w3});
//    each x element -> 1 pk_fma computing 2 wires (32->16 issues/sample,
//    no horizontal add; acc[t][w] = pair halves).
//  - GEMM: postW rows held transposed as output-pair x q-dim float2; per out
//    row 32 FMA -> 16 pk_fma.
// Everything else verbatim R15 (LDS angle hand-off + syncthreads, split-state
// circuit, plain float4 stores). Kept: R7/R9/R14 lessons.
// Predict: dur 43.5-45, VALUBusy 14->11-12% profiled; else ROOFLINE at R15.

typedef float floatx4 __attribute__((ext_vector_type(4)));
typedef float floatx2 __attribute__((ext_vector_type(2)));

static __device__ __forceinline__ floatx2 mk2(float a, float b)
{
    floatx2 r; r.x = a; r.y = b; return r;
}

static __device__ __forceinline__ void st_store4(float* p, floatx4 v)
{
    *reinterpret_cast<floatx4*>(p) = v;
}

static __device__ __forceinline__ float fast_tanh(float a)
{
    a = fminf(fmaxf(a, -15.f), 15.f);
    const float e = __expf(2.f * a);
    return (e - 1.f) / (e + 1.f);
}

// ---- split-state Rot helpers (R15, unchanged) ----
template<int ST>
__device__ __forceinline__ void rot_inlane(float* ar, float* ai,
    float u00r, float u00i, float u01r, float u01i,
    float u10r, float u10i, float u11r, float u11i)
{
#pragma unroll
    for (int k = 0; k < 4; ++k) {
        if (k & ST) continue;
        const int j = k | ST;
        const float Ar = ar[k], Ai = ai[k], Br = ar[j], Bi = ai[j];
        ar[k] = u00r*Ar - u00i*Ai + u01r*Br - u01i*Bi;
        ai[k] = u00r*Ai + u00i*Ar + u01r*Bi + u01i*Br;
        ar[j] = u10r*Ar - u10i*Ai + u11r*Br - u11i*Bi;
        ai[j] = u10r*Ai + u10i*Ar + u11r*Bi + u11i*Br;
    }
}

template<int XM>
__device__ __forceinline__ void rot_cross(float* ar, float* ai, bool ownB,
    float u00r, float u00i, float u01r, float u01i,
    float u10r, float u10i, float u11r, float u11i)
{
    const float cAr = ownB ? u11r : u00r;
    const float cAi = ownB ? u11i : u00i;
    const float cBr = ownB ? u10r : u01r;
    const float cBi = ownB ? u10i : u01i;
#pragma unroll
    for (int k = 0; k < 4; ++k) {
        const float pr = __shfl_xor(ar[k], XM, 64);
        const float pi = __shfl_xor(ai[k], XM, 64);
        const float vr = ar[k], vi = ai[k];
        ar[k] = cAr*vr - cAi*vi + cBr*pr - cBi*pi;
        ai[k] = cAr*vi + cAi*vr + cBr*pi + cBi*pr;
    }
}

#define ROT_COEFFS(L, W) \
    const float ph = wts[((L)*4+(W))*3+0]; \
    const float th = wts[((L)*4+(W))*3+1]; \
    const float om = wts[((L)*4+(W))*3+2]; \
    const float s_  = __sinf(0.5f*th),        c_  = __cosf(0.5f*th); \
    const float sp_ = __sinf(0.5f*(ph+om)),   cp_ = __cosf(0.5f*(ph+om)); \
    const float sq_ = __sinf(0.5f*(ph-om)),   cq_ = __cosf(0.5f*(ph-om));

#define U_ARGS cp_*c_, -sp_*c_, -cq_*s_, -sq_*s_, cq_*s_, -sq_*s_, cp_*c_, sp_*c_

// Block = 256 threads = 4 waves = 64 samples (R15 structure).
__global__ __launch_bounds__(256) void k_fused(
    const float* __restrict__ x,
    const float* __restrict__ preW,
    const float* __restrict__ preb,
    const float* __restrict__ wts,
    const float* __restrict__ postW,
    const float* __restrict__ postb,
    float* __restrict__ out, int B)
{
    const int lane  = threadIdx.x & 63;
    const int wid   = threadIdx.x >> 6;          // wave in block, 0..3
    const int base  = blockIdx.x * 64;           // 64 samples per block
    const int wbase = base + wid * 16;           // this wave's 16 samples
    if (base >= B) return;

    __shared__ float4 angLds[64];                // [sampleLocal] -> 4 angles

    // ---------- Phase 1: angles — packed-FP32 dot ----------
    // Held preW fragments, TRANSPOSED into wire-pair float2s:
    // wT01[e] = {preW[w0][elem e], preW[w1][elem e]}, e in 0..7 (4 from A half, 4 from B half)
    floatx2 wT01[8], wT23[8];
    {
        float4 wA[4], wB[4];
#pragma unroll
        for (int w = 0; w < 4; ++w) {
            wA[w] = *reinterpret_cast<const float4*>(preW + w * 512 + lane * 4);
            wB[w] = *reinterpret_cast<const float4*>(preW + w * 512 + 256 + lane * 4);
        }
        wT01[0] = mk2(wA[0].x, wA[1].x); wT01[1] = mk2(wA[0].y, wA[1].y);
        wT01[2] = mk2(wA[0].z, wA[1].z); wT01[3] = mk2(wA[0].w, wA[1].w);
        wT01[4] = mk2(wB[0].x, wB[1].x); wT01[5] = mk2(wB[0].y, wB[1].y);
        wT01[6] = mk2(wB[0].z, wB[1].z); wT01[7] = mk2(wB[0].w, wB[1].w);
        wT23[0] = mk2(wA[2].x, wA[3].x); wT23[1] = mk2(wA[2].y, wA[3].y);
        wT23[2] = mk2(wA[2].z, wA[3].z); wT23[3] = mk2(wA[2].w, wA[3].w);
        wT23[4] = mk2(wB[2].x, wB[3].x); wT23[5] = mk2(wB[2].y, wB[3].y);
        wT23[6] = mk2(wB[2].z, wB[3].z); wT23[7] = mk2(wB[2].w, wB[3].w);
    }
    const float4 pb = *reinterpret_cast<const float4*>(preb);

#pragma unroll
    for (int p = 0; p < 4; ++p) {
        const int b0 = wbase + p * 4;

        float4 xa[4], xb[4];
#pragma unroll
        for (int t = 0; t < 4; ++t) {
            const float* xr = x + (size_t)(b0 + t) * 512;
            xa[t] = *reinterpret_cast<const float4*>(xr + lane * 4);
            xb[t] = *reinterpret_cast<const float4*>(xr + 256 + lane * 4);
        }

        float acc[4][4];
#pragma unroll
        for (int t = 0; t < 4; ++t) {
            // 16 pk_fma computes all 4 wires (was 32 scalar FMA)
            floatx2 a01 = wT01[0] * xa[t].x;
            a01 += wT01[1] * xa[t].y;
            a01 += wT01[2] * xa[t].z;
            a01 += wT01[3] * xa[t].w;
            a01 += wT01[4] * xb[t].x;
            a01 += wT01[5] * xb[t].y;
            a01 += wT01[6] * xb[t].z;
            a01 += wT01[7] * xb[t].w;
            floatx2 a23 = wT23[0] * xa[t].x;
            a23 += wT23[1] * xa[t].y;
            a23 += wT23[2] * xa[t].z;
            a23 += wT23[3] * xa[t].w;
            a23 += wT23[4] * xb[t].x;
            a23 += wT23[5] * xb[t].y;
            a23 += wT23[6] * xb[t].z;
            a23 += wT23[7] * xb[t].w;
            acc[t][0] = a01.x; acc[t][1] = a01.y;
            acc[t][2] = a23.x; acc[t][3] = a23.y;
        }

        // 17-shfl fold (verbatim): lane l (<16) holds dot(sample b0+(l>>2), wire l&3)
        float v[4];
#pragma unroll
        for (int t = 0; t < 4; ++t) {
            float a01 = (lane & 1) ? acc[t][1] : acc[t][0];
            float b01 = (lane & 1) ? acc[t][0] : acc[t][1];
            a01 += __shfl_xor(b01, 1, 64);
            float a23 = (lane & 1) ? acc[t][3] : acc[t][2];
            float b23 = (lane & 1) ? acc[t][2] : acc[t][3];
            a23 += __shfl_xor(b23, 1, 64);
            const float vv = (lane & 2) ? a23 : a01;
            const float uu = (lane & 2) ? a01 : a23;
            v[t] = vv + __shfl_xor(uu, 2, 64);
        }
        float c01 = (lane & 4) ? v[1] : v[0];
        float d01 = (lane & 4) ? v[0] : v[1];
        c01 += __shfl_xor(d01, 4, 64);
        float c23 = (lane & 4) ? v[3] : v[2];
        float d23 = (lane & 4) ? v[2] : v[3];
        c23 += __shfl_xor(d23, 4, 64);
        float m = (lane & 8) ? c23 : c01;
        float n = (lane & 8) ? c01 : c23;
        m += __shfl_xor(n, 8, 64);
        m += __shfl_xor(m, 16, 64);
        m += __shfl_xor(m, 32, 64);

        const float pb01 = (lane & 1) ? pb.y : pb.x;
        const float pb23 = (lane & 1) ? pb.w : pb.z;
        const float pbv  = (lane & 2) ? pb23 : pb01;
        const float angv = fast_tanh(m + pbv) * PI_F;

        if (lane < 16) {
            float* arow = reinterpret_cast<float*>(&angLds[wid * 16 + p * 4 + (lane >> 2)]);
            arow[lane & 3] = angv;
        }
    }

    __syncthreads();

    // ---------- Phase 2: SPLIT-STATE circuit (R15, unchanged) ----------
    const int  sid = lane >> 2;                  // sample in wave, 0..15
    const bool lb3 = (lane & 2) != 0;            // amp bit3 (wire0)
    const bool lb2 = (lane & 1) != 0;            // amp bit2 (wire1)
    const float4 ang = angLds[wid * 16 + sid];

    const float s0 = __sinf(0.5f * ang.x), c0 = __cosf(0.5f * ang.x);
    const float s1 = __sinf(0.5f * ang.y), c1 = __cosf(0.5f * ang.y);
    const float s2 = __sinf(0.5f * ang.z), c2 = __cosf(0.5f * ang.z);
    const float s3 = __sinf(0.5f * ang.w), c3 = __cosf(0.5f * ang.w);

    const float mhi = (lb3 ? s0 : c0) * (lb2 ? s1 : c1);
    const float hr  = lb3 ? (lb2 ? -mhi : 0.f) : (lb2 ? 0.f : mhi);
    const float hi  = (lb3 != lb2) ? -mhi : 0.f;
    const float low0 = c2 * c3, low1 = c2 * s3, low2 = s2 * c3, low3 = s2 * s3;

    float ar[4], ai[4];
    ar[0] =  hr * low0;  ai[0] =  hi * low0;
    ar[1] =  hi * low1;  ai[1] = -hr * low1;
    ar[2] =  hi * low2;  ai[2] = -hr * low2;
    ar[3] = -hr * low3;  ai[3] = -hi * low3;

    // ---- layer 0 ----
    { ROT_COEFFS(0, 0); rot_cross<2>(ar, ai, lb3, U_ARGS); }
    { ROT_COEFFS(0, 1); rot_cross<1>(ar, ai, lb2, U_ARGS); }
    { ROT_COEFFS(0, 2); rot_inlane<2>(ar, ai, U_ARGS); }
    { ROT_COEFFS(0, 3); rot_inlane<1>(ar, ai, U_ARGS); }

    {   // cnot<0,1>
#pragma unroll
        for (int k = 0; k < 4; ++k) {
            const float tr = __shfl_xor(ar[k], 1, 64);
            const float ti = __shfl_xor(ai[k], 1, 64);
            ar[k] = lb3 ? tr : ar[k];
            ai[k] = lb3 ? ti : ai[k];
        }
    }
    {   // cnot<1,2>
        const float t0r = ar[0], t0i = ai[0], t1r = ar[1], t1i = ai[1];
        ar[0] = lb2 ? ar[2] : ar[0];  ai[0] = lb2 ? ai[2] : ai[0];
        ar[1] = lb2 ? ar[3] : ar[1];  ai[1] = lb2 ? ai[3] : ai[1];
        ar[2] = lb2 ? t0r   : ar[2];  ai[2] = lb2 ? t0i   : ai[2];
        ar[3] = lb2 ? t1r   : ar[3];  ai[3] = lb2 ? t1i   : ai[3];
    }
    {   // cnot<2,3>: in-lane swap k2<->k3
        float t;
        t = ar[2]; ar[2] = ar[3]; ar[3] = t;
        t = ai[2]; ai[2] = ai[3]; ai[3] = t;
    }
    {   // cnot<3,0>: k in {1,3} exchange across lane^2
        ar[1] = __shfl_xor(ar[1], 2, 64);  ai[1] = __shfl_xor(ai[1], 2, 64);
        ar[3] = __shfl_xor(ar[3], 2, 64);  ai[3] = __shfl_xor(ai[3], 2, 64);
    }

    // ---- layer 1 ----
    { ROT_COEFFS(1, 0); rot_cross<2>(ar, ai, lb3, U_ARGS); }
    { ROT_COEFFS(1, 1); rot_cross<1>(ar, ai, lb2, U_ARGS); }
    { ROT_COEFFS(1, 2); rot_inlane<2>(ar, ai, U_ARGS); }
    { ROT_COEFFS(1, 3); rot_inlane<1>(ar, ai, U_ARGS); }

    {   // cnot<0,2>
        const float t0r = ar[0], t0i = ai[0], t1r = ar[1], t1i = ai[1];
        ar[0] = lb3 ? ar[2] : ar[0];  ai[0] = lb3 ? ai[2] : ai[0];
        ar[1] = lb3 ? ar[3] : ar[1];  ai[1] = lb3 ? ai[3] : ai[1];
        ar[2] = lb3 ? t0r   : ar[2];  ai[2] = lb3 ? t0i   : ai[2];
        ar[3] = lb3 ? t1r   : ar[3];  ai[3] = lb3 ? t1i   : ai[3];
    }
    {   // cnot<1,3>
        const float t0r = ar[0], t0i = ai[0], t2r = ar[2], t2i = ai[2];
        ar[0] = lb2 ? ar[1] : ar[0];  ai[0] = lb2 ? ai[1] : ai[0];
        ar[1] = lb2 ? t0r   : ar[1];  ai[1] = lb2 ? t0i   : ai[1];
        ar[2] = lb2 ? ar[3] : ar[2];  ai[2] = lb2 ? ai[3] : ai[2];
        ar[3] = lb2 ? t2r   : ar[3];  ai[3] = lb2 ? t2i   : ai[3];
    }
    {   // cnot<2,0>: k in {2,3} exchange across lane^2
        ar[2] = __shfl_xor(ar[2], 2, 64);  ai[2] = __shfl_xor(ai[2], 2, 64);
        ar[3] = __shfl_xor(ar[3], 2, 64);  ai[3] = __shfl_xor(ai[3], 2, 64);
    }
    {   // cnot<3,1>: k in {1,3} exchange across lane^1
        ar[1] = __shfl_xor(ar[1], 1, 64);  ai[1] = __shfl_xor(ai[1], 1, 64);
        ar[3] = __shfl_xor(ar[3], 1, 64);  ai[3] = __shfl_xor(ai[3], 1, 64);
    }

    // ---- PauliZ expvals: per-lane partials + 4-lane group xor-reduce ----
    const float p0 = ar[0]*ar[0] + ai[0]*ai[0];
    const float p1 = ar[1]*ar[1] + ai[1]*ai[1];
    const float p2 = ar[2]*ar[2] + ai[2]*ai[2];
    const float p3 = ar[3]*ar[3] + ai[3]*ai[3];
    const float s01 = p0 + p1, s23 = p2 + p3;
    const float sum = s01 + s23;
    float z0 = lb3 ? -sum : sum;
    float z1 = lb2 ? -sum : sum;
    float z2 = s01 - s23;
    float z3 = (p0 - p1) + (p2 - p3);
    z0 += __shfl_xor(z0, 1, 64);  z0 += __shfl_xor(z0, 2, 64);
    z1 += __shfl_xor(z1, 1, 64);  z1 += __shfl_xor(z1, 2, 64);
    z2 += __shfl_xor(z2, 1, 64);  z2 += __shfl_xor(z2, 2, 64);
    z3 += __shfl_xor(z3, 1, 64);  z3 += __shfl_xor(z3, 2, 64);

    // ---------- Phase 3: out GEMM — packed-FP32 ----------
    // postW rows held transposed into output-pair x q-dim float2s:
    // Wab[j] = {postW[colA][j], postW[colB][j]} for output pairs (4l+0,4l+1),
    // (4l+2,4l+3), (256+4l+0, +1), (256+4l+2, +3).
    const float4* pW4 = reinterpret_cast<const float4*>(postW);
    const float4* pb4 = reinterpret_cast<const float4*>(postb);
    const float4 q0w = pW4[4 * lane + 0], q1w = pW4[4 * lane + 1];
    const float4 q2w = pW4[4 * lane + 2], q3w = pW4[4 * lane + 3];
    const float4 q4w = pW4[4 * (64 + lane) + 0], q5w = pW4[4 * (64 + lane) + 1];
    const float4 q6w = pW4[4 * (64 + lane) + 2], q7w = pW4[4 * (64 + lane) + 3];
    const float4 bb0 = pb4[lane], bb1 = pb4[64 + lane];

    floatx2 W01[4] = { mk2(q0w.x,q1w.x), mk2(q0w.y,q1w.y), mk2(q0w.z,q1w.z), mk2(q0w.w,q1w.w) };
    floatx2 W23[4] = { mk2(q2w.x,q3w.x), mk2(q2w.y,q3w.y), mk2(q2w.z,q3w.z), mk2(q2w.w,q3w.w) };
    floatx2 W45[4] = { mk2(q4w.x,q5w.x), mk2(q4w.y,q5w.y), mk2(q4w.z,q5w.z), mk2(q4w.w,q5w.w) };
    floatx2 W67[4] = { mk2(q6w.x,q7w.x), mk2(q6w.y,q7w.y), mk2(q6w.z,q7w.z), mk2(q6w.w,q7w.w) };
    const floatx2 B01 = mk2(bb0.x, bb0.y), B23 = mk2(bb0.z, bb0.w);
    const floatx2 B45 = mk2(bb1.x, bb1.y), B67 = mk2(bb1.z, bb1.w);

#pragma unroll
    for (int s = 0; s < 16; ++s) {
        const float q0 = __shfl(z0, s * 4, 64);
        const float q1 = __shfl(z1, s * 4, 64);
        const float q2 = __shfl(z2, s * 4, 64);
        const float q3 = __shfl(z3, s * 4, 64);
        floatx2 r01 = B01, r23 = B23, r45 = B45, r67 = B67;
        r01 += W01[0] * q0;  r01 += W01[1] * q1;  r01 += W01[2] * q2;  r01 += W01[3] * q3;
        r23 += W23[0] * q0;  r23 += W23[1] * q1;  r23 += W23[2] * q2;  r23 += W23[3] * q3;
        r45 += W45[0] * q0;  r45 += W45[1] * q1;  r45 += W45[2] * q2;  r45 += W45[3] * q3;
        r67 += W67[0] * q0;  r67 += W67[1] * q1;  r67 += W67[2] * q2;  r67 += W67[3] * q3;
        floatx4 o0, o1;
        o0.x = r01.x; o0.y = r01.y; o0.z = r23.x; o0.w = r23.y;
        o1.x = r45.x; o1.y = r45.y; o1.z = r67.x; o1.w = r67.y;
        float* orow = out + (size_t)(wbase + s) * 512;
        st_store4(orow + 4 * lane, o0);
        st_store4(orow + 256 + 4 * lane, o1);
    }
}

extern "C" void kernel_launch(void* const* d_in, const int* in_sizes, int n_in,
                              void* d_out, int out_size, void* d_ws, size_t ws_size,
                              hipStream_t stream)
{
    const float* x     = (const float*)d_in[0];
    const float* preW  = (const float*)d_in[1];
    const float* preb  = (const float*)d_in[2];
    const float* wts   = (const float*)d_in[3];
    const float* postW = (const float*)d_in[4];
    const float* postb = (const float*)d_in[5];
    float* out = (float*)d_out;
    const int B = in_sizes[0] / 512;

    // 4 waves/block, 64 samples/block
    k_fused<<<dim3((B + 63) / 64), dim3(256), 0, stream>>>(
        x, preW, preb, wts, postW, postb, out, B);
}